// Round 1
// baseline (16.182 us; speedup 1.0000x reference)
//
#include <hip/hip_runtime.h>

// Semantic_Loss_89386859364662
// ref: hist over channels {0,8,10} of LAST batch element of each input,
//      loss = L1(hA,hP) / (L1(hA,hN) + 1e-7), scalar f32 output.
// Inputs: 3 x [8,19,512,512] f32. Only batch index 7 is read.

#define HW (512 * 512)
#define NBINS 256
#define LAST_IMG_OFF ((size_t)7 * 19 * HW)

__global__ void zero_hist(unsigned int* __restrict__ hist) {
    int t = blockIdx.x * blockDim.x + threadIdx.x;
    if (t < 3 * NBINS) hist[t] = 0u;
}

__global__ void hist_kernel(const float* __restrict__ in0,
                            const float* __restrict__ in1,
                            const float* __restrict__ in2,
                            unsigned int* __restrict__ hist) {
    __shared__ unsigned int sh[NBINS];
    const int input = blockIdx.y;                       // 0..2
    const float* src = (input == 0) ? in0 : (input == 1) ? in1 : in2;

    for (int i = threadIdx.x; i < NBINS; i += blockDim.x) sh[i] = 0u;
    __syncthreads();

    const float SCALE = (float)(256.0 / 255.0);         // matches jnp f32 scale
    const int NV4 = 3 * HW / 4;                         // 196608 float4 loads
    const int stride = gridDim.x * blockDim.x;
    const int chans[3] = {0, 8, 10};

    for (int j = blockIdx.x * blockDim.x + threadIdx.x; j < NV4; j += stride) {
        const int ch   = j >> 16;                       // j / (HW/4), HW/4 = 65536
        const int pix4 = j & 0xFFFF;                    // j % (HW/4)
        const float4 v = *reinterpret_cast<const float4*>(
            src + LAST_IMG_OFF + (size_t)chans[ch] * HW + (size_t)pix4 * 4);
        const float vals[4] = {v.x, v.y, v.z, v.w};
#pragma unroll
        for (int k = 0; k < 4; ++k) {
            const int idx = (int)floorf(vals[k] * SCALE);
            if (idx >= 0 && idx < NBINS) atomicAdd(&sh[idx], 1u);
        }
    }
    __syncthreads();

    for (int i = threadIdx.x; i < NBINS; i += blockDim.x) {
        const unsigned int c = sh[i];
        if (c) atomicAdd(&hist[input * NBINS + i], c);
    }
}

__global__ void loss_kernel(const unsigned int* __restrict__ hist,
                            float* __restrict__ out) {
    __shared__ float s1w[4], s2w[4];
    const int t = threadIdx.x;                          // 256 threads, 1 block
    const float a = (float)hist[t];
    const float p = (float)hist[NBINS + t];
    const float n = (float)hist[2 * NBINS + t];
    float d1 = fabsf(a - p);
    float d2 = fabsf(a - n);
    // wave64 butterfly-free down-reduce
#pragma unroll
    for (int off = 32; off > 0; off >>= 1) {
        d1 += __shfl_down(d1, off);
        d2 += __shfl_down(d2, off);
    }
    const int wave = t >> 6;
    if ((t & 63) == 0) { s1w[wave] = d1; s2w[wave] = d2; }
    __syncthreads();
    if (t == 0) {
        const float s1 = s1w[0] + s1w[1] + s1w[2] + s1w[3];
        const float s2 = s2w[0] + s2w[1] + s2w[2] + s2w[3];
        const float l1ap = s1 * (1.0f / 256.0f);        // jnp.mean over 256 bins
        const float l1an = s2 * (1.0f / 256.0f);
        out[0] = l1ap / (l1an + 1e-7f);
    }
}

extern "C" void kernel_launch(void* const* d_in, const int* in_sizes, int n_in,
                              void* d_out, int out_size, void* d_ws, size_t ws_size,
                              hipStream_t stream) {
    const float* restored = (const float*)d_in[0];
    const float* positive = (const float*)d_in[1];
    const float* negative = (const float*)d_in[2];
    unsigned int* hist = (unsigned int*)d_ws;           // 3*256*4 = 3 KiB scratch
    float* out = (float*)d_out;

    zero_hist<<<dim3(3), 256, 0, stream>>>(hist);
    hist_kernel<<<dim3(96, 3), 256, 0, stream>>>(restored, positive, negative, hist);
    loss_kernel<<<1, 256, 0, stream>>>(hist, out);
}